// Round 1
// baseline (883.405 us; speedup 1.0000x reference)
//
#include <hip/hip_runtime.h>
#include <hip/hip_bf16.h>

#define IN_DIM 128
#define NUM_HEADS 8
#define OUT_DIM 16

// ---------------- Projection: out[n][c] = sum_k h[n][k] * W[k][c] + b[c] ----------------
// Block = 256 threads, handles 16 nodes x 128 cols. h tile staged in LDS transposed
// ([k][node]) so the 8-node register-blocked inner loop reads are LDS broadcasts.
__global__ __launch_bounds__(256) void proj_kernel(const float* __restrict__ h,
                                                   const float* __restrict__ W,
                                                   const float* __restrict__ b,
                                                   float* __restrict__ out,
                                                   int nNodes) {
    __shared__ float hs[128][17];  // [k][node], padded
    const int node0 = blockIdx.x * 16;
    const int t = threadIdx.x;

    // load 16 rows of h (2048 floats) with 256 threads
    #pragma unroll
    for (int r = 0; r < 8; ++r) {
        int idx = t + r * 256;      // 0..2047
        int node = idx >> 7;
        int k = idx & 127;
        hs[k][node] = h[(size_t)(node0 + node) * IN_DIM + k];
    }
    __syncthreads();

    const int col = t & 127;
    const int nset = (t >> 7) * 8;  // 0 or 8
    float acc[8];
    const float bias = b[col];
    #pragma unroll
    for (int r = 0; r < 8; ++r) acc[r] = bias;

    for (int k = 0; k < 128; ++k) {
        float w = W[k * 128 + col];  // coalesced across 128 lanes; W is L2-hot
        #pragma unroll
        for (int r = 0; r < 8; ++r) acc[r] += hs[k][nset + r] * w;
    }

    #pragma unroll
    for (int r = 0; r < 8; ++r)
        out[(size_t)(node0 + nset + r) * 128 + col] = acc[r];
}

// ---------------- Edge kernel: one wave (64 lanes) per edge ----------------
// lane i owns flattened dims {2i, 2i+1} of [H=8][D=16]; a head = 8 consecutive lanes.
__global__ __launch_bounds__(256) void edge_kernel(const int* __restrict__ src,
                                                   const int* __restrict__ dst,
                                                   const float* __restrict__ Q,
                                                   const float* __restrict__ K,
                                                   const float* __restrict__ V,
                                                   float* __restrict__ wV,
                                                   float* __restrict__ z,
                                                   int nEdges) {
    int wid = (int)((blockIdx.x * (size_t)blockDim.x + threadIdx.x) >> 6);
    if (wid >= nEdges) return;
    const int lane = threadIdx.x & 63;
    const int s = src[wid];
    const int d = dst[wid];

    const float2* Ks = (const float2*)(K + (size_t)s * 128);
    const float2* Qd = (const float2*)(Q + (size_t)d * 128);
    const float2* Vs = (const float2*)(V + (size_t)s * 128);

    float2 kv = Ks[lane];
    float2 qv = Qd[lane];
    float p = kv.x * qv.x + kv.y * qv.y;
    // reduce over the 8-lane head group (16 dims, 2/lane)
    p += __shfl_xor(p, 1);
    p += __shfl_xor(p, 2);
    p += __shfl_xor(p, 4);

    float score = p * 0.25f;                       // 1/sqrt(16)
    score = fminf(fmaxf(score, -5.0f), 5.0f);
    float e = expf(score);

    float2 vv = Vs[lane];
    atomicAdd(&wV[(size_t)d * 128 + 2 * lane], vv.x * e);
    atomicAdd(&wV[(size_t)d * 128 + 2 * lane + 1], vv.y * e);
    if ((lane & 7) == 0) atomicAdd(&z[(size_t)d * 8 + (lane >> 3)], e);
}

// ---------------- Finalize: out /= (z + 1e-6) ----------------
__global__ __launch_bounds__(256) void finalize_kernel(float* __restrict__ out,
                                                       const float* __restrict__ z,
                                                       int n) {
    int i = blockIdx.x * blockDim.x + threadIdx.x;
    if (i >= n) return;
    int node = i >> 7;
    int head = (i >> 4) & 7;
    out[i] = out[i] / (z[node * 8 + head] + 1e-6f);
}

extern "C" void kernel_launch(void* const* d_in, const int* in_sizes, int n_in,
                              void* d_out, int out_size, void* d_ws, size_t ws_size,
                              hipStream_t stream) {
    const float* h   = (const float*)d_in[0];
    const int*   src = (const int*)d_in[1];
    const int*   dst = (const int*)d_in[2];
    const float* WQ  = (const float*)d_in[3];
    const float* bQ  = (const float*)d_in[4];
    const float* WK  = (const float*)d_in[5];
    const float* bK  = (const float*)d_in[6];
    const float* WV  = (const float*)d_in[7];
    const float* bV  = (const float*)d_in[8];

    const int nNodes = in_sizes[0] / IN_DIM;
    const int nEdges = in_sizes[1];

    float* out = (float*)d_out;
    const size_t nodeFeats = (size_t)nNodes * 128;
    float* Qw = (float*)d_ws;
    float* Kw = Qw + nodeFeats;
    float* Vw = Kw + nodeFeats;
    float* zw = Vw + nodeFeats;

    // zero accumulators (graph-capture-safe async memsets)
    hipMemsetAsync(d_out, 0, nodeFeats * sizeof(float), stream);
    hipMemsetAsync(zw, 0, (size_t)nNodes * NUM_HEADS * sizeof(float), stream);

    // projections
    int projBlocks = (nNodes + 15) / 16;
    proj_kernel<<<projBlocks, 256, 0, stream>>>(h, WQ, bQ, Qw, nNodes);
    proj_kernel<<<projBlocks, 256, 0, stream>>>(h, WK, bK, Kw, nNodes);
    proj_kernel<<<projBlocks, 256, 0, stream>>>(h, WV, bV, Vw, nNodes);

    // edge scatter: one wave per edge, 4 waves per block
    int edgeBlocks = (nEdges + 3) / 4;
    edge_kernel<<<edgeBlocks, 256, 0, stream>>>(src, dst, Qw, Kw, Vw, out, zw, nEdges);

    // finalize
    int n = nNodes * 128;
    finalize_kernel<<<(n + 255) / 256, 256, 0, stream>>>(out, zw, n);
}

// Round 2
// 416.509 us; speedup vs baseline: 2.1210x; 2.1210x over previous
//
#include <hip/hip_runtime.h>
#include <hip/hip_bf16.h>

#define IN_DIM 128
#define NUM_HEADS 8
#define OUT_DIM 16

// ---------------- Projection: out[n][c] = sum_k h[n][k] * W[k][c] + b[c] ----------------
__global__ __launch_bounds__(256) void proj_kernel(const float* __restrict__ h,
                                                   const float* __restrict__ W,
                                                   const float* __restrict__ b,
                                                   float* __restrict__ out,
                                                   int nNodes) {
    __shared__ float hs[128][17];  // [k][node], padded
    const int node0 = blockIdx.x * 16;
    const int t = threadIdx.x;

    #pragma unroll
    for (int r = 0; r < 8; ++r) {
        int idx = t + r * 256;      // 0..2047
        int node = idx >> 7;
        int k = idx & 127;
        hs[k][node] = h[(size_t)(node0 + node) * IN_DIM + k];
    }
    __syncthreads();

    const int col = t & 127;
    const int nset = (t >> 7) * 8;  // 0 or 8
    float acc[8];
    const float bias = b[col];
    #pragma unroll
    for (int r = 0; r < 8; ++r) acc[r] = bias;

    for (int k = 0; k < 128; ++k) {
        float w = W[k * 128 + col];
        #pragma unroll
        for (int r = 0; r < 8; ++r) acc[r] += hs[k][nset + r] * w;
    }

    #pragma unroll
    for (int r = 0; r < 8; ++r)
        out[(size_t)(node0 + nset + r) * 128 + col] = acc[r];
}

// ---------------- CSR build ----------------
__global__ __launch_bounds__(256) void hist_kernel(const int* __restrict__ dst,
                                                   int* __restrict__ counts, int nEdges) {
    int e = blockIdx.x * blockDim.x + threadIdx.x;
    if (e < nEdges) atomicAdd(&counts[dst[e]], 1);
}

// single-block exclusive scan, 1024 threads, shfl within waves + LDS across 16 waves
__global__ __launch_bounds__(1024) void scan_kernel(const int* __restrict__ counts,
                                                    int* __restrict__ offsets, int n) {
    __shared__ int waveSums[16];
    __shared__ int carry;
    const int lane = threadIdx.x & 63;
    const int wv = threadIdx.x >> 6;
    if (threadIdx.x == 0) carry = 0;
    __syncthreads();
    for (int base = 0; base < n; base += 1024) {
        int i = base + threadIdx.x;
        int v = (i < n) ? counts[i] : 0;
        int x = v;
        #pragma unroll
        for (int off = 1; off < 64; off <<= 1) {
            int y = __shfl_up(x, off);
            if (lane >= off) x += y;
        }
        if (lane == 63) waveSums[wv] = x;
        __syncthreads();
        if (threadIdx.x < 16) {
            int s = waveSums[threadIdx.x];
            #pragma unroll
            for (int off = 1; off < 16; off <<= 1) {
                int y = __shfl_up(s, off);
                if ((int)threadIdx.x >= off) s += y;
            }
            waveSums[threadIdx.x] = s;
        }
        __syncthreads();
        int waveOff = (wv == 0) ? 0 : waveSums[wv - 1];
        int incl = x + waveOff + carry;           // reads carry BEFORE the barrier below
        if (i < n) offsets[i] = incl - v;         // exclusive
        __syncthreads();
        if (threadIdx.x == 0) carry += waveSums[15];
        __syncthreads();
    }
    if (threadIdx.x == 0) offsets[n] = carry;
}

__global__ __launch_bounds__(256) void scatter_kernel(const int* __restrict__ src,
                                                      const int* __restrict__ dst,
                                                      const int* __restrict__ offsets,
                                                      int* __restrict__ cursor,
                                                      int* __restrict__ srcSorted,
                                                      int nEdges) {
    int e = blockIdx.x * blockDim.x + threadIdx.x;
    if (e >= nEdges) return;
    int d = dst[e];
    int pos = offsets[d] + atomicAdd(&cursor[d], 1);
    srcSorted[pos] = src[e];
}

// ---------------- Aggregation: one wave per dst node, all accumulation in registers ----------------
// lane i owns dims {2i, 2i+1} of [H=8][D=16]; within an 8-lane head group every lane's
// post-reduce score is identical, so z accumulates without any cross-lane traffic.
__global__ __launch_bounds__(256) void agg_kernel(const int* __restrict__ offsets,
                                                  const int* __restrict__ srcSorted,
                                                  const float* __restrict__ Q,
                                                  const float* __restrict__ K,
                                                  const float* __restrict__ V,
                                                  float* __restrict__ out,
                                                  int nNodes) {
    int wid = (int)((blockIdx.x * (size_t)blockDim.x + threadIdx.x) >> 6);
    if (wid >= nNodes) return;
    const int lane = threadIdx.x & 63;
    const int beg = offsets[wid];
    const int end = offsets[wid + 1];

    const float2 qv = ((const float2*)(Q + (size_t)wid * 128))[lane];
    float2 acc = {0.f, 0.f};
    float zacc = 0.f;

    for (int j = beg; j < end; ++j) {
        int s = srcSorted[j];
        float2 kv = ((const float2*)(K + (size_t)s * 128))[lane];
        float2 vv = ((const float2*)(V + (size_t)s * 128))[lane];
        float p = kv.x * qv.x + kv.y * qv.y;
        p += __shfl_xor(p, 1);
        p += __shfl_xor(p, 2);
        p += __shfl_xor(p, 4);
        float sc = fminf(fmaxf(p * 0.25f, -5.0f), 5.0f);
        float e = __expf(sc);
        acc.x += vv.x * e;
        acc.y += vv.y * e;
        zacc += e;
    }

    float denom = zacc + 1e-6f;
    float2 o = {acc.x / denom, acc.y / denom};
    ((float2*)(out + (size_t)wid * 128))[lane] = o;
}

extern "C" void kernel_launch(void* const* d_in, const int* in_sizes, int n_in,
                              void* d_out, int out_size, void* d_ws, size_t ws_size,
                              hipStream_t stream) {
    const float* h   = (const float*)d_in[0];
    const int*   src = (const int*)d_in[1];
    const int*   dst = (const int*)d_in[2];
    const float* WQ  = (const float*)d_in[3];
    const float* bQ  = (const float*)d_in[4];
    const float* WK  = (const float*)d_in[5];
    const float* bK  = (const float*)d_in[6];
    const float* WV  = (const float*)d_in[7];
    const float* bV  = (const float*)d_in[8];

    const int nNodes = in_sizes[0] / IN_DIM;
    const int nEdges = in_sizes[1];

    float* out = (float*)d_out;
    const size_t nodeFeats = (size_t)nNodes * 128;

    float* Qw = (float*)d_ws;
    float* Kw = Qw + nodeFeats;
    float* Vw = Kw + nodeFeats;
    int* offsets   = (int*)(Vw + nodeFeats);        // nNodes+1
    int* counts    = offsets + (nNodes + 1);        // nNodes
    int* cursor    = counts + nNodes;               // nNodes
    int* srcSorted = cursor + nNodes;               // nEdges

    hipMemsetAsync(counts, 0, (size_t)nNodes * sizeof(int), stream);
    hipMemsetAsync(cursor, 0, (size_t)nNodes * sizeof(int), stream);

    // CSR build
    int eb = (nEdges + 255) / 256;
    hist_kernel<<<eb, 256, 0, stream>>>(dst, counts, nEdges);
    scan_kernel<<<1, 1024, 0, stream>>>(counts, offsets, nNodes);
    scatter_kernel<<<eb, 256, 0, stream>>>(src, dst, offsets, cursor, srcSorted, nEdges);

    // projections
    int projBlocks = (nNodes + 15) / 16;
    proj_kernel<<<projBlocks, 256, 0, stream>>>(h, WQ, bQ, Qw, nNodes);
    proj_kernel<<<projBlocks, 256, 0, stream>>>(h, WK, bK, Kw, nNodes);
    proj_kernel<<<projBlocks, 256, 0, stream>>>(h, WV, bV, Vw, nNodes);

    // aggregation: one wave per node, 4 waves per block
    int aggBlocks = (nNodes * 64 + 255) / 256;
    agg_kernel<<<aggBlocks, 256, 0, stream>>>(offsets, srcSorted, Qw, Kw, Vw, out, nNodes);
}

// Round 3
// 241.362 us; speedup vs baseline: 3.6601x; 1.7257x over previous
//
#include <hip/hip_runtime.h>
#include <hip/hip_bf16.h>

#define IN_DIM 128
#define NUM_HEADS 8
#define OUT_DIM 16

typedef unsigned int uint;

__device__ inline uint bf16_rne(float x) {
    uint u = __float_as_uint(x);
    return (u + 0x7fffu + ((u >> 16) & 1u)) >> 16;
}

// ---------------- Fused projection: Q (f32), KV (packed bf16 pairs) ----------------
// Block = 256 threads, 16 nodes x 128 cols. h tile staged once in LDS transposed.
__global__ __launch_bounds__(256) void proj_fused(const float* __restrict__ h,
                                                  const float* __restrict__ WQ, const float* __restrict__ bQ,
                                                  const float* __restrict__ WK, const float* __restrict__ bK,
                                                  const float* __restrict__ WV, const float* __restrict__ bV,
                                                  float* __restrict__ Qout, uint* __restrict__ KVout,
                                                  int nNodes) {
    __shared__ float hs[128][17];  // [k][node], padded (17 odd -> conflict-free)
    const int node0 = blockIdx.x * 16;
    const int t = threadIdx.x;

    #pragma unroll
    for (int r = 0; r < 8; ++r) {
        int idx = t + r * 256;      // 0..2047
        int node = idx >> 7;
        int k = idx & 127;
        hs[k][node] = h[(size_t)(node0 + node) * IN_DIM + k];
    }
    __syncthreads();

    const int col = t & 127;
    const int nset = (t >> 7) * 8;  // 0 or 8
    float aq[8], ak[8], av[8];
    const float biasq = bQ[col], biask = bK[col], biasv = bV[col];
    #pragma unroll
    for (int r = 0; r < 8; ++r) { aq[r] = biasq; ak[r] = biask; av[r] = biasv; }

    for (int k = 0; k < 128; ++k) {
        float wq = WQ[k * 128 + col];
        float wk = WK[k * 128 + col];
        float wv = WV[k * 128 + col];
        #pragma unroll
        for (int r = 0; r < 8; ++r) {
            float hv = hs[k][nset + r];
            aq[r] += hv * wq;
            ak[r] += hv * wk;
            av[r] += hv * wv;
        }
    }

    #pragma unroll
    for (int r = 0; r < 8; ++r) {
        size_t node = (size_t)(node0 + nset + r);
        Qout[node * 128 + col] = aq[r];
        KVout[node * 128 + col] = bf16_rne(ak[r]) | (bf16_rne(av[r]) << 16);
    }
}

// ---------------- CSR build ----------------
__global__ __launch_bounds__(256) void hist_kernel(const int* __restrict__ dst,
                                                   int* __restrict__ counts, int nEdges) {
    int e = blockIdx.x * blockDim.x + threadIdx.x;
    if (e < nEdges) atomicAdd(&counts[dst[e]], 1);
}

// partial scan: each block scans a 1024-element chunk (4/thread), writes chunk-exclusive
// prefixes to partial[] and the chunk total to blockSums[blockIdx].
__global__ __launch_bounds__(256) void scan_partial(const int* __restrict__ counts,
                                                    int* __restrict__ partial,
                                                    int* __restrict__ blockSums, int n) {
    __shared__ int ws[4];
    const int t = threadIdx.x;
    const int lane = t & 63;
    const int wv = t >> 6;
    const int i = blockIdx.x * 1024 + t * 4;

    int4 v = {0, 0, 0, 0};
    if (i + 3 < n) v = *(const int4*)(counts + i);
    else {
        if (i < n) v.x = counts[i];
        if (i + 1 < n) v.y = counts[i + 1];
        if (i + 2 < n) v.z = counts[i + 2];
        if (i + 3 < n) v.w = counts[i + 3];
    }
    int s = v.x + v.y + v.z + v.w;
    int x = s;
    #pragma unroll
    for (int off = 1; off < 64; off <<= 1) {
        int y = __shfl_up(x, off);
        if (lane >= off) x += y;
    }
    if (lane == 63) ws[wv] = x;
    __syncthreads();
    if (t == 0) {
        int a = 0;
        #pragma unroll
        for (int w = 0; w < 4; ++w) { int tmp = ws[w]; ws[w] = a; a += tmp; }
        blockSums[blockIdx.x] = a;
    }
    __syncthreads();
    int prefix = ws[wv] + (x - s);  // exclusive prefix of this thread's 4 elements
    int4 o;
    o.x = prefix;
    o.y = prefix + v.x;
    o.z = o.y + v.y;
    o.w = o.z + v.z;
    if (i + 3 < n) *(int4*)(partial + i) = o;
    else {
        if (i < n) partial[i] = o.x;
        if (i + 1 < n) partial[i + 1] = o.y;
        if (i + 2 < n) partial[i + 2] = o.z;
        if (i + 3 < n) partial[i + 3] = o.w;
    }
}

// single-wave exclusive scan of <=64 block sums
__global__ __launch_bounds__(64) void scan_sums(const int* __restrict__ blockSums,
                                                int* __restrict__ blockOffs, int nb) {
    int lane = threadIdx.x;
    int v = (lane < nb) ? blockSums[lane] : 0;
    int x = v;
    #pragma unroll
    for (int off = 1; off < 64; off <<= 1) {
        int y = __shfl_up(x, off);
        if (lane >= off) x += y;
    }
    if (lane < nb) blockOffs[lane] = x - v;
}

__global__ __launch_bounds__(256) void add_offsets(const int* __restrict__ partial,
                                                   const int* __restrict__ blockOffs,
                                                   int* __restrict__ offsets, int n, int nEdges) {
    int i = blockIdx.x * blockDim.x + threadIdx.x;
    if (i < n) offsets[i] = partial[i] + blockOffs[i >> 10];
    else if (i == n) offsets[n] = nEdges;
}

// scatter: cursor[] is a copy of offsets[]; atomicAdd gives final slot directly
__global__ __launch_bounds__(256) void scatter_kernel(const int* __restrict__ src,
                                                      const int* __restrict__ dst,
                                                      int* __restrict__ cursor,
                                                      int* __restrict__ srcSorted,
                                                      int nEdges) {
    int e = blockIdx.x * blockDim.x + threadIdx.x;
    if (e >= nEdges) return;
    int pos = atomicAdd(&cursor[dst[e]], 1);
    srcSorted[pos] = src[e];
}

// ---------------- Aggregation: one wave per dst node ----------------
// lane i owns dims {2i,2i+1}; a head = 8 consecutive lanes. KV row: 128 uints,
// uint d = bf16(K_d) | bf16(V_d)<<16 -> lane loads ONE uint2 per edge.
__device__ inline void agg_step(uint2 u, float2 qv, float& ax, float& ay, float& zacc) {
    float k0 = __uint_as_float((u.x & 0xffffu) << 16);
    float v0 = __uint_as_float(u.x & 0xffff0000u);
    float k1 = __uint_as_float((u.y & 0xffffu) << 16);
    float v1 = __uint_as_float(u.y & 0xffff0000u);
    float p = k0 * qv.x + k1 * qv.y;
    p += __shfl_xor(p, 1);
    p += __shfl_xor(p, 2);
    p += __shfl_xor(p, 4);
    float sc = fminf(fmaxf(p * 0.25f, -5.0f), 5.0f);
    float e = __expf(sc);
    ax += v0 * e;
    ay += v1 * e;
    zacc += e;
}

__global__ __launch_bounds__(256) void agg_kernel(const int* __restrict__ offsets,
                                                  const int* __restrict__ srcSorted,
                                                  const float* __restrict__ Q,
                                                  const uint2* __restrict__ KV,  // row stride 64 uint2
                                                  float* __restrict__ out,
                                                  int nNodes) {
    int wid = (int)((blockIdx.x * (size_t)blockDim.x + threadIdx.x) >> 6);
    if (wid >= nNodes) return;
    const int lane = threadIdx.x & 63;
    const int beg = offsets[wid];
    const int end = offsets[wid + 1];

    const float2 qv = ((const float2*)(Q + (size_t)wid * 128))[lane];
    float ax = 0.f, ay = 0.f, zacc = 0.f;

    int j = beg;
    for (; j + 4 <= end; j += 4) {
        int s0 = srcSorted[j];
        int s1 = srcSorted[j + 1];
        int s2 = srcSorted[j + 2];
        int s3 = srcSorted[j + 3];
        uint2 u0 = KV[(size_t)s0 * 64 + lane];
        uint2 u1 = KV[(size_t)s1 * 64 + lane];
        uint2 u2 = KV[(size_t)s2 * 64 + lane];
        uint2 u3 = KV[(size_t)s3 * 64 + lane];
        agg_step(u0, qv, ax, ay, zacc);
        agg_step(u1, qv, ax, ay, zacc);
        agg_step(u2, qv, ax, ay, zacc);
        agg_step(u3, qv, ax, ay, zacc);
    }
    for (; j < end; ++j) {
        uint2 u = KV[(size_t)srcSorted[j] * 64 + lane];
        agg_step(u, qv, ax, ay, zacc);
    }

    float denom = zacc + 1e-6f;
    float2 o = {ax / denom, ay / denom};
    ((float2*)(out + (size_t)wid * 128))[lane] = o;
}

extern "C" void kernel_launch(void* const* d_in, const int* in_sizes, int n_in,
                              void* d_out, int out_size, void* d_ws, size_t ws_size,
                              hipStream_t stream) {
    const float* h   = (const float*)d_in[0];
    const int*   src = (const int*)d_in[1];
    const int*   dst = (const int*)d_in[2];
    const float* WQ  = (const float*)d_in[3];
    const float* bQ  = (const float*)d_in[4];
    const float* WK  = (const float*)d_in[5];
    const float* bK  = (const float*)d_in[6];
    const float* WV  = (const float*)d_in[7];
    const float* bV  = (const float*)d_in[8];

    const int nNodes = in_sizes[0] / IN_DIM;
    const int nEdges = in_sizes[1];

    float* out = (float*)d_out;
    const size_t nf = (size_t)nNodes * 128;

    float* Qw       = (float*)d_ws;              // nf f32
    uint*  KVw      = (uint*)(Qw + nf);          // nf u32
    int*   counts   = (int*)(KVw + nf);          // nNodes (16B aligned)
    int*   partial  = counts + nNodes;           // nNodes
    int*   srcSorted= partial + nNodes;          // nEdges
    int*   offsets  = srcSorted + nEdges;        // nNodes+1
    int*   cursor   = offsets + (nNodes + 1);    // nNodes
    int*   blockSums= cursor + nNodes;           // 64
    int*   blockOffs= blockSums + 64;            // 64

    const int nb = (nNodes + 1023) / 1024;       // 49 <= 64

    hipMemsetAsync(counts, 0, (size_t)nNodes * sizeof(int), stream);

    int eb = (nEdges + 255) / 256;
    hist_kernel<<<eb, 256, 0, stream>>>(dst, counts, nEdges);
    scan_partial<<<nb, 256, 0, stream>>>(counts, partial, blockSums, nNodes);
    scan_sums<<<1, 64, 0, stream>>>(blockSums, blockOffs, nb);
    add_offsets<<<(nNodes + 256) / 256, 256, 0, stream>>>(partial, blockOffs, offsets, nNodes, nEdges);
    hipMemcpyAsync(cursor, offsets, (size_t)nNodes * sizeof(int), hipMemcpyDeviceToDevice, stream);
    scatter_kernel<<<eb, 256, 0, stream>>>(src, dst, cursor, srcSorted, nEdges);

    proj_fused<<<(nNodes + 15) / 16, 256, 0, stream>>>(h, WQ, bQ, WK, bK, WV, bV, Qw, KVw, nNodes);

    int aggBlocks = (nNodes * 64 + 255) / 256;
    agg_kernel<<<aggBlocks, 256, 0, stream>>>(offsets, srcSorted, Qw, (const uint2*)KVw, out, nNodes);
}

// Round 4
// 222.128 us; speedup vs baseline: 3.9770x; 1.0866x over previous
//
#include <hip/hip_runtime.h>
#include <hip/hip_bf16.h>

#define IN_DIM 128
#define NUM_HEADS 8
#define OUT_DIM 16

typedef unsigned int uint;
typedef unsigned short ushort;
using short8 = __attribute__((ext_vector_type(8))) short;
using f32x4  = __attribute__((ext_vector_type(4))) float;

__device__ inline uint bf16_rne(float x) {
    uint u = __float_as_uint(x);
    return (u + 0x7fffu + ((u >> 16) & 1u)) >> 16;
}

// ---------------- W transpose+convert: WT[n][k] bf16, n in [0,384) = {WQ|WK|WV} cols ----------------
__global__ __launch_bounds__(256) void wtrans_kernel(const float* __restrict__ WQ,
                                                     const float* __restrict__ WK,
                                                     const float* __restrict__ WV,
                                                     ushort* __restrict__ WT) {
    int tid = blockIdx.x * 256 + threadIdx.x;   // 0..6143
    if (tid >= 384 * 16) return;
    int n = tid >> 4;           // 0..383
    int kg = tid & 15;          // 16B group: k = kg*8 .. kg*8+7
    const float* W = (n < 128) ? WQ : (n < 256) ? WK : WV;
    int c = n & 127;
    short8 o;
    #pragma unroll
    for (int j = 0; j < 8; ++j) {
        float v = W[(kg * 8 + j) * 128 + c];
        o[j] = (short)bf16_rne(v);
    }
    *(short8*)(WT + (size_t)n * 128 + kg * 8) = o;
}

// ---------------- MFMA projection: 64 nodes/block, 4 waves, Q f32 + packed bf16 KV ----------------
__global__ __launch_bounds__(256) void proj_mfma(const float* __restrict__ h,
                                                 const short* __restrict__ WT,   // [384][128] bf16
                                                 const float* __restrict__ bQ,
                                                 const float* __restrict__ bK,
                                                 const float* __restrict__ bV,
                                                 float* __restrict__ Qout,
                                                 uint* __restrict__ KVout,
                                                 int nNodes) {
    __shared__ short8 hT[1024];   // 64 rows x 128 cols bf16, swizzled in 16B slots
    const int t = threadIdx.x;
    const int node0 = blockIdx.x * 64;

    // stage h -> bf16 LDS (each thread 4x 16B groups)
    #pragma unroll
    for (int i = 0; i < 4; ++i) {
        int g = t + i * 256;        // 0..1023
        int row = g >> 4;
        int grp = g & 15;
        short8 val;
        if (node0 + row < nNodes) {
            const float* src = h + (size_t)(node0 + row) * 128 + grp * 8;
            float4 f0 = *(const float4*)src;
            float4 f1 = *(const float4*)(src + 4);
            val[0] = (short)bf16_rne(f0.x); val[1] = (short)bf16_rne(f0.y);
            val[2] = (short)bf16_rne(f0.z); val[3] = (short)bf16_rne(f0.w);
            val[4] = (short)bf16_rne(f1.x); val[5] = (short)bf16_rne(f1.y);
            val[6] = (short)bf16_rne(f1.z); val[7] = (short)bf16_rne(f1.w);
        } else {
            val = (short8)0;
        }
        hT[(row * 16 + grp) ^ (row & 7)] = val;
    }
    __syncthreads();

    const int lane = t & 63;
    const int w = t >> 6;            // wave 0..3 -> rows w*16..w*16+15
    const int lr = lane & 15;
    const int q = lane >> 4;

    // A fragments: 4 k-slices of this wave's 16 rows
    short8 a[4];
    #pragma unroll
    for (int ks = 0; ks < 4; ++ks) {
        int row = w * 16 + lr;
        a[ks] = hT[(row * 16 + ks * 4 + q) ^ (row & 7)];
    }

    const short8* WT8 = (const short8*)WT;   // [384][16]

    #pragma unroll 2
    for (int c = 0; c < 8; ++c) {
        f32x4 accQ = {0.f, 0.f, 0.f, 0.f};
        f32x4 accK = {0.f, 0.f, 0.f, 0.f};
        f32x4 accV = {0.f, 0.f, 0.f, 0.f};
        const int nq = c * 16 + lr;          // output col 0..127
        #pragma unroll
        for (int ks = 0; ks < 4; ++ks) {
            short8 bq = WT8[(size_t)nq * 16 + ks * 4 + q];
            short8 bk = WT8[(size_t)(nq + 128) * 16 + ks * 4 + q];
            short8 bv = WT8[(size_t)(nq + 256) * 16 + ks * 4 + q];
            accQ = __builtin_amdgcn_mfma_f32_16x16x32_bf16(a[ks], bq, accQ, 0, 0, 0);
            accK = __builtin_amdgcn_mfma_f32_16x16x32_bf16(a[ks], bk, accK, 0, 0, 0);
            accV = __builtin_amdgcn_mfma_f32_16x16x32_bf16(a[ks], bv, accV, 0, 0, 0);
        }
        float biasq = bQ[nq];
        float biask = bK[nq];
        float biasv = bV[nq];
        #pragma unroll
        for (int r = 0; r < 4; ++r) {
            int node = node0 + w * 16 + q * 4 + r;
            if (node < nNodes) {
                Qout[(size_t)node * 128 + nq] = accQ[r] + biasq;
                KVout[(size_t)node * 128 + nq] =
                    bf16_rne(accK[r] + biask) | (bf16_rne(accV[r] + biasv) << 16);
            }
        }
    }
}

// ---------------- CSR build ----------------
__global__ __launch_bounds__(256) void hist_kernel(const int* __restrict__ dst,
                                                   int* __restrict__ counts, int nEdges) {
    int e = blockIdx.x * blockDim.x + threadIdx.x;
    if (e < nEdges) atomicAdd(&counts[dst[e]], 1);
}

__global__ __launch_bounds__(256) void scan_partial(const int* __restrict__ counts,
                                                    int* __restrict__ partial,
                                                    int* __restrict__ blockSums, int n) {
    __shared__ int ws[4];
    const int t = threadIdx.x;
    const int lane = t & 63;
    const int wv = t >> 6;
    const int i = blockIdx.x * 1024 + t * 4;

    int4 v = {0, 0, 0, 0};
    if (i + 3 < n) v = *(const int4*)(counts + i);
    else {
        if (i < n) v.x = counts[i];
        if (i + 1 < n) v.y = counts[i + 1];
        if (i + 2 < n) v.z = counts[i + 2];
        if (i + 3 < n) v.w = counts[i + 3];
    }
    int s = v.x + v.y + v.z + v.w;
    int x = s;
    #pragma unroll
    for (int off = 1; off < 64; off <<= 1) {
        int y = __shfl_up(x, off);
        if (lane >= off) x += y;
    }
    if (lane == 63) ws[wv] = x;
    __syncthreads();
    if (t == 0) {
        int a = 0;
        #pragma unroll
        for (int w = 0; w < 4; ++w) { int tmp = ws[w]; ws[w] = a; a += tmp; }
        blockSums[blockIdx.x] = a;
    }
    __syncthreads();
    int prefix = ws[wv] + (x - s);
    int4 o;
    o.x = prefix;
    o.y = prefix + v.x;
    o.z = o.y + v.y;
    o.w = o.z + v.z;
    if (i + 3 < n) *(int4*)(partial + i) = o;
    else {
        if (i < n) partial[i] = o.x;
        if (i + 1 < n) partial[i + 1] = o.y;
        if (i + 2 < n) partial[i + 2] = o.z;
        if (i + 3 < n) partial[i + 3] = o.w;
    }
}

__global__ __launch_bounds__(64) void scan_sums(const int* __restrict__ blockSums,
                                                int* __restrict__ blockOffs, int nb) {
    int lane = threadIdx.x;
    int v = (lane < nb) ? blockSums[lane] : 0;
    int x = v;
    #pragma unroll
    for (int off = 1; off < 64; off <<= 1) {
        int y = __shfl_up(x, off);
        if (lane >= off) x += y;
    }
    if (lane < nb) blockOffs[lane] = x - v;
}

__global__ __launch_bounds__(256) void add_offsets(const int* __restrict__ partial,
                                                   const int* __restrict__ blockOffs,
                                                   int* __restrict__ offsets, int n, int nEdges) {
    int i = blockIdx.x * blockDim.x + threadIdx.x;
    if (i < n) offsets[i] = partial[i] + blockOffs[i >> 10];
    else if (i == n) offsets[n] = nEdges;
}

__global__ __launch_bounds__(256) void scatter_kernel(const int* __restrict__ src,
                                                      const int* __restrict__ dst,
                                                      int* __restrict__ cursor,
                                                      int* __restrict__ srcSorted,
                                                      int nEdges) {
    int e = blockIdx.x * blockDim.x + threadIdx.x;
    if (e >= nEdges) return;
    int pos = atomicAdd(&cursor[dst[e]], 1);
    srcSorted[pos] = src[e];
}

// ---------------- Aggregation: one wave per dst node ----------------
__device__ inline void agg_step(uint2 u, float2 qv, float& ax, float& ay, float& zacc) {
    float k0 = __uint_as_float((u.x & 0xffffu) << 16);
    float v0 = __uint_as_float(u.x & 0xffff0000u);
    float k1 = __uint_as_float((u.y & 0xffffu) << 16);
    float v1 = __uint_as_float(u.y & 0xffff0000u);
    float p = k0 * qv.x + k1 * qv.y;
    p += __shfl_xor(p, 1);
    p += __shfl_xor(p, 2);
    p += __shfl_xor(p, 4);
    float sc = fminf(fmaxf(p * 0.25f, -5.0f), 5.0f);
    float e = __expf(sc);
    ax += v0 * e;
    ay += v1 * e;
    zacc += e;
}

__global__ __launch_bounds__(256) void agg_kernel(const int* __restrict__ offsets,
                                                  const int* __restrict__ srcSorted,
                                                  const float* __restrict__ Q,
                                                  const uint2* __restrict__ KV,
                                                  float* __restrict__ out,
                                                  int nNodes) {
    int wid = (int)((blockIdx.x * (size_t)blockDim.x + threadIdx.x) >> 6);
    if (wid >= nNodes) return;
    const int lane = threadIdx.x & 63;
    const int beg = offsets[wid];
    const int end = offsets[wid + 1];

    const float2 qv = ((const float2*)(Q + (size_t)wid * 128))[lane];
    float ax = 0.f, ay = 0.f, zacc = 0.f;

    int j = beg;
    for (; j + 4 <= end; j += 4) {
        int s0 = srcSorted[j];
        int s1 = srcSorted[j + 1];
        int s2 = srcSorted[j + 2];
        int s3 = srcSorted[j + 3];
        uint2 u0 = KV[(size_t)s0 * 64 + lane];
        uint2 u1 = KV[(size_t)s1 * 64 + lane];
        uint2 u2 = KV[(size_t)s2 * 64 + lane];
        uint2 u3 = KV[(size_t)s3 * 64 + lane];
        agg_step(u0, qv, ax, ay, zacc);
        agg_step(u1, qv, ax, ay, zacc);
        agg_step(u2, qv, ax, ay, zacc);
        agg_step(u3, qv, ax, ay, zacc);
    }
    for (; j < end; ++j) {
        uint2 u = KV[(size_t)srcSorted[j] * 64 + lane];
        agg_step(u, qv, ax, ay, zacc);
    }

    float denom = zacc + 1e-6f;
    float2 o = {ax / denom, ay / denom};
    ((float2*)(out + (size_t)wid * 128))[lane] = o;
}

extern "C" void kernel_launch(void* const* d_in, const int* in_sizes, int n_in,
                              void* d_out, int out_size, void* d_ws, size_t ws_size,
                              hipStream_t stream) {
    const float* h   = (const float*)d_in[0];
    const int*   src = (const int*)d_in[1];
    const int*   dst = (const int*)d_in[2];
    const float* WQ  = (const float*)d_in[3];
    const float* bQ  = (const float*)d_in[4];
    const float* WK  = (const float*)d_in[5];
    const float* bK  = (const float*)d_in[6];
    const float* WV  = (const float*)d_in[7];
    const float* bV  = (const float*)d_in[8];

    const int nNodes = in_sizes[0] / IN_DIM;
    const int nEdges = in_sizes[1];

    float* out = (float*)d_out;
    const size_t nf = (size_t)nNodes * 128;

    float*  Qw       = (float*)d_ws;                 // nf f32
    uint*   KVw      = (uint*)(Qw + nf);             // nf u32
    ushort* WTw      = (ushort*)(KVw + nf);          // 384*128 bf16 (96KB, 16B aligned)
    int*    counts   = (int*)(WTw + 384 * 128);      // nNodes
    int*    partial  = counts + nNodes;              // nNodes
    int*    srcSorted= partial + nNodes;             // nEdges
    int*    offsets  = srcSorted + nEdges;           // nNodes+1
    int*    cursor   = offsets + (nNodes + 1);       // nNodes
    int*    blockSums= cursor + nNodes;              // 64
    int*    blockOffs= blockSums + 64;               // 64

    const int nb = (nNodes + 1023) / 1024;           // 49 <= 64

    hipMemsetAsync(counts, 0, (size_t)nNodes * sizeof(int), stream);

    // W transpose (tiny) — independent of CSR chain
    wtrans_kernel<<<24, 256, 0, stream>>>(WQ, WK, WV, WTw);

    // CSR build
    int eb = (nEdges + 255) / 256;
    hist_kernel<<<eb, 256, 0, stream>>>(dst, counts, nEdges);
    scan_partial<<<nb, 256, 0, stream>>>(counts, partial, blockSums, nNodes);
    scan_sums<<<1, 64, 0, stream>>>(blockSums, blockOffs, nb);
    add_offsets<<<(nNodes + 256) / 256, 256, 0, stream>>>(partial, blockOffs, offsets, nNodes, nEdges);
    hipMemcpyAsync(cursor, offsets, (size_t)nNodes * sizeof(int), hipMemcpyDeviceToDevice, stream);
    scatter_kernel<<<eb, 256, 0, stream>>>(src, dst, cursor, srcSorted, nEdges);

    // MFMA projections
    proj_mfma<<<(nNodes + 63) / 64, 256, 0, stream>>>(h, (const short*)WTw, bQ, bK, bV, Qw, KVw, nNodes);

    // aggregation
    int aggBlocks = (nNodes * 64 + 255) / 256;
    agg_kernel<<<aggBlocks, 256, 0, stream>>>(offsets, srcSorted, Qw, (const uint2*)KVw, out, nNodes);
}

// Round 5
// 215.783 us; speedup vs baseline: 4.0940x; 1.0294x over previous
//
#include <hip/hip_runtime.h>
#include <hip/hip_bf16.h>

#define IN_DIM 128
#define NUM_HEADS 8
#define OUT_DIM 16

typedef unsigned int uint;
typedef unsigned short ushort;
using short8 = __attribute__((ext_vector_type(8))) short;
using f32x4  = __attribute__((ext_vector_type(4))) float;

__device__ inline uint bf16_rne(float x) {
    uint u = __float_as_uint(x);
    return (u + 0x7fffu + ((u >> 16) & 1u)) >> 16;
}

// ---------------- W transpose+convert: WT[n][k] bf16, n in [0,384) = {WQ|WK|WV} cols ----------------
__global__ __launch_bounds__(256) void wtrans_kernel(const float* __restrict__ WQ,
                                                     const float* __restrict__ WK,
                                                     const float* __restrict__ WV,
                                                     ushort* __restrict__ WT) {
    int tid = blockIdx.x * 256 + threadIdx.x;   // 0..6143
    if (tid >= 384 * 16) return;
    int n = tid >> 4;           // 0..383
    int kg = tid & 15;          // 16B group: k = kg*8 .. kg*8+7
    const float* W = (n < 128) ? WQ : (n < 256) ? WK : WV;
    int c = n & 127;
    short8 o;
    #pragma unroll
    for (int j = 0; j < 8; ++j) {
        float v = W[(kg * 8 + j) * 128 + c];
        o[j] = (short)bf16_rne(v);
    }
    *(short8*)(WT + (size_t)n * 128 + kg * 8) = o;
}

// ---------------- MFMA projection: 64 nodes/block, 4 waves, Q f32 + packed bf16 KV ----------------
__global__ __launch_bounds__(256) void proj_mfma(const float* __restrict__ h,
                                                 const short* __restrict__ WT,   // [384][128] bf16
                                                 const float* __restrict__ bQ,
                                                 const float* __restrict__ bK,
                                                 const float* __restrict__ bV,
                                                 float* __restrict__ Qout,
                                                 uint* __restrict__ KVout,
                                                 int nNodes) {
    __shared__ short8 hT[1024];   // 64 rows x 128 cols bf16, swizzled in 16B slots
    const int t = threadIdx.x;
    const int node0 = blockIdx.x * 64;

    #pragma unroll
    for (int i = 0; i < 4; ++i) {
        int g = t + i * 256;        // 0..1023
        int row = g >> 4;
        int grp = g & 15;
        short8 val;
        if (node0 + row < nNodes) {
            const float* src = h + (size_t)(node0 + row) * 128 + grp * 8;
            float4 f0 = *(const float4*)src;
            float4 f1 = *(const float4*)(src + 4);
            val[0] = (short)bf16_rne(f0.x); val[1] = (short)bf16_rne(f0.y);
            val[2] = (short)bf16_rne(f0.z); val[3] = (short)bf16_rne(f0.w);
            val[4] = (short)bf16_rne(f1.x); val[5] = (short)bf16_rne(f1.y);
            val[6] = (short)bf16_rne(f1.z); val[7] = (short)bf16_rne(f1.w);
        } else {
            val = (short8)0;
        }
        hT[(row * 16 + grp) ^ (row & 7)] = val;
    }
    __syncthreads();

    const int lane = t & 63;
    const int w = t >> 6;
    const int lr = lane & 15;
    const int q = lane >> 4;

    short8 a[4];
    #pragma unroll
    for (int ks = 0; ks < 4; ++ks) {
        int row = w * 16 + lr;
        a[ks] = hT[(row * 16 + ks * 4 + q) ^ (row & 7)];
    }

    const short8* WT8 = (const short8*)WT;   // [384][16]

    #pragma unroll 2
    for (int c = 0; c < 8; ++c) {
        f32x4 accQ = {0.f, 0.f, 0.f, 0.f};
        f32x4 accK = {0.f, 0.f, 0.f, 0.f};
        f32x4 accV = {0.f, 0.f, 0.f, 0.f};
        const int nq = c * 16 + lr;
        #pragma unroll
        for (int ks = 0; ks < 4; ++ks) {
            short8 bq = WT8[(size_t)nq * 16 + ks * 4 + q];
            short8 bk = WT8[(size_t)(nq + 128) * 16 + ks * 4 + q];
            short8 bv = WT8[(size_t)(nq + 256) * 16 + ks * 4 + q];
            accQ = __builtin_amdgcn_mfma_f32_16x16x32_bf16(a[ks], bq, accQ, 0, 0, 0);
            accK = __builtin_amdgcn_mfma_f32_16x16x32_bf16(a[ks], bk, accK, 0, 0, 0);
            accV = __builtin_amdgcn_mfma_f32_16x16x32_bf16(a[ks], bv, accV, 0, 0, 0);
        }
        float biasq = bQ[nq];
        float biask = bK[nq];
        float biasv = bV[nq];
        #pragma unroll
        for (int r = 0; r < 4; ++r) {
            int node = node0 + w * 16 + q * 4 + r;
            if (node < nNodes) {
                Qout[(size_t)node * 128 + nq] = accQ[r] + biasq;
                KVout[(size_t)node * 128 + nq] =
                    bf16_rne(accK[r] + biask) | (bf16_rne(accV[r] + biasv) << 16);
            }
        }
    }
}

// ---------------- CSR build ----------------
__global__ __launch_bounds__(256) void hist_kernel(const int* __restrict__ dst,
                                                   int* __restrict__ counts, int nEdges) {
    int e4 = (blockIdx.x * blockDim.x + threadIdx.x) * 4;
    if (e4 + 3 < nEdges) {
        int4 d = *(const int4*)(dst + e4);
        atomicAdd(&counts[d.x], 1);
        atomicAdd(&counts[d.y], 1);
        atomicAdd(&counts[d.z], 1);
        atomicAdd(&counts[d.w], 1);
    } else {
        for (int e = e4; e < nEdges; ++e) atomicAdd(&counts[dst[e]], 1);
    }
}

__global__ __launch_bounds__(256) void scan_partial(const int* __restrict__ counts,
                                                    int* __restrict__ partial,
                                                    int* __restrict__ blockSums, int n) {
    __shared__ int ws[4];
    const int t = threadIdx.x;
    const int lane = t & 63;
    const int wv = t >> 6;
    const int i = blockIdx.x * 1024 + t * 4;

    int4 v = {0, 0, 0, 0};
    if (i + 3 < n) v = *(const int4*)(counts + i);
    else {
        if (i < n) v.x = counts[i];
        if (i + 1 < n) v.y = counts[i + 1];
        if (i + 2 < n) v.z = counts[i + 2];
        if (i + 3 < n) v.w = counts[i + 3];
    }
    int s = v.x + v.y + v.z + v.w;
    int x = s;
    #pragma unroll
    for (int off = 1; off < 64; off <<= 1) {
        int y = __shfl_up(x, off);
        if (lane >= off) x += y;
    }
    if (lane == 63) ws[wv] = x;
    __syncthreads();
    if (t == 0) {
        int a = 0;
        #pragma unroll
        for (int w = 0; w < 4; ++w) { int tmp = ws[w]; ws[w] = a; a += tmp; }
        blockSums[blockIdx.x] = a;
    }
    __syncthreads();
    int prefix = ws[wv] + (x - s);
    int4 o;
    o.x = prefix;
    o.y = prefix + v.x;
    o.z = o.y + v.y;
    o.w = o.z + v.z;
    if (i + 3 < n) *(int4*)(partial + i) = o;
    else {
        if (i < n) partial[i] = o.x;
        if (i + 1 < n) partial[i + 1] = o.y;
        if (i + 2 < n) partial[i + 2] = o.z;
        if (i + 3 < n) partial[i + 3] = o.w;
    }
}

__global__ __launch_bounds__(64) void scan_sums(const int* __restrict__ blockSums,
                                                int* __restrict__ blockOffs, int nb) {
    int lane = threadIdx.x;
    int v = (lane < nb) ? blockSums[lane] : 0;
    int x = v;
    #pragma unroll
    for (int off = 1; off < 64; off <<= 1) {
        int y = __shfl_up(x, off);
        if (lane >= off) x += y;
    }
    if (lane < nb) blockOffs[lane] = x - v;
}

// writes offsets AND cursor (cursor = working copy for scatter)
__global__ __launch_bounds__(256) void add_offsets(const int* __restrict__ partial,
                                                   const int* __restrict__ blockOffs,
                                                   int* __restrict__ offsets,
                                                   int* __restrict__ cursor, int n, int nEdges) {
    int i = blockIdx.x * blockDim.x + threadIdx.x;
    if (i < n) {
        int v = partial[i] + blockOffs[i >> 10];
        offsets[i] = v;
        cursor[i] = v;
    } else if (i == n) {
        offsets[n] = nEdges;
    }
}

__global__ __launch_bounds__(256) void scatter_kernel(const int* __restrict__ src,
                                                      const int* __restrict__ dst,
                                                      int* __restrict__ cursor,
                                                      int* __restrict__ srcSorted,
                                                      int nEdges) {
    int e4 = (blockIdx.x * blockDim.x + threadIdx.x) * 4;
    if (e4 + 3 < nEdges) {
        int4 d = *(const int4*)(dst + e4);
        int4 s = *(const int4*)(src + e4);
        srcSorted[atomicAdd(&cursor[d.x], 1)] = s.x;
        srcSorted[atomicAdd(&cursor[d.y], 1)] = s.y;
        srcSorted[atomicAdd(&cursor[d.z], 1)] = s.z;
        srcSorted[atomicAdd(&cursor[d.w], 1)] = s.w;
    } else {
        for (int e = e4; e < nEdges; ++e)
            srcSorted[atomicAdd(&cursor[dst[e]], 1)] = src[e];
    }
}

// ---------------- Aggregation: one wave per dst node, 2 edges in parallel per wave ----------------
// lanes 0-31 = edge stream A, lanes 32-63 = edge stream B. Lane li=lane&31 owns dims
// 4*li..4*li+3 (one uint4 of packed bf16 K|V). Head = 4 lanes -> 2-step shfl reduce.
__global__ __launch_bounds__(256) void agg_kernel(const int* __restrict__ offsets,
                                                  const int* __restrict__ srcSorted,
                                                  const float* __restrict__ Q,
                                                  const uint4* __restrict__ KV,   // row = 32 uint4
                                                  float* __restrict__ out,
                                                  int nNodes) {
    int wid = (int)((blockIdx.x * (size_t)blockDim.x + threadIdx.x) >> 6);
    if (wid >= nNodes) return;
    const int lane = threadIdx.x & 63;
    const int li = lane & 31;
    const int hf = lane >> 5;
    const int beg = offsets[wid];
    const int end = offsets[wid + 1];

    const float4 qv = ((const float4*)(Q + (size_t)wid * 128))[li];
    float4 acc = {0.f, 0.f, 0.f, 0.f};
    float zacc = 0.f;

    auto compute = [&](uint4 u, float mask) {
        float k0 = __uint_as_float(u.x << 16), v0 = __uint_as_float(u.x & 0xffff0000u);
        float k1 = __uint_as_float(u.y << 16), v1 = __uint_as_float(u.y & 0xffff0000u);
        float k2 = __uint_as_float(u.z << 16), v2 = __uint_as_float(u.z & 0xffff0000u);
        float k3 = __uint_as_float(u.w << 16), v3 = __uint_as_float(u.w & 0xffff0000u);
        float p = k0 * qv.x + k1 * qv.y + k2 * qv.z + k3 * qv.w;
        p += __shfl_xor(p, 1);
        p += __shfl_xor(p, 2);
        float e = __expf(fminf(fmaxf(p * 0.25f, -5.0f), 5.0f)) * mask;
        acc.x += v0 * e; acc.y += v1 * e; acc.z += v2 * e; acc.w += v3 * e;
        zacc += e;
    };

    int j = beg;
    for (; j + 8 <= end; j += 8) {
        int s0 = srcSorted[j     + hf];
        int s1 = srcSorted[j + 2 + hf];
        int s2 = srcSorted[j + 4 + hf];
        int s3 = srcSorted[j + 6 + hf];
        uint4 u0 = KV[(size_t)s0 * 32 + li];
        uint4 u1 = KV[(size_t)s1 * 32 + li];
        uint4 u2 = KV[(size_t)s2 * 32 + li];
        uint4 u3 = KV[(size_t)s3 * 32 + li];
        compute(u0, 1.f);
        compute(u1, 1.f);
        compute(u2, 1.f);
        compute(u3, 1.f);
    }
    for (; j + 2 <= end; j += 2) {
        int s = srcSorted[j + hf];
        uint4 u = KV[(size_t)s * 32 + li];
        compute(u, 1.f);
    }
    if (j < end) {  // one edge left: stream A active, stream B masked
        int s = srcSorted[j];
        uint4 u = KV[(size_t)s * 32 + li];
        compute(u, hf ? 0.f : 1.f);
    }

    // combine the two halves
    acc.x += __shfl_xor(acc.x, 32);
    acc.y += __shfl_xor(acc.y, 32);
    acc.z += __shfl_xor(acc.z, 32);
    acc.w += __shfl_xor(acc.w, 32);
    zacc  += __shfl_xor(zacc, 32);

    if (hf == 0) {
        float inv = 1.0f / (zacc + 1e-6f);
        float4 o = {acc.x * inv, acc.y * inv, acc.z * inv, acc.w * inv};
        ((float4*)(out + (size_t)wid * 128))[li] = o;
    }
}

extern "C" void kernel_launch(void* const* d_in, const int* in_sizes, int n_in,
                              void* d_out, int out_size, void* d_ws, size_t ws_size,
                              hipStream_t stream) {
    const float* h   = (const float*)d_in[0];
    const int*   src = (const int*)d_in[1];
    const int*   dst = (const int*)d_in[2];
    const float* WQ  = (const float*)d_in[3];
    const float* bQ  = (const float*)d_in[4];
    const float* WK  = (const float*)d_in[5];
    const float* bK  = (const float*)d_in[6];
    const float* WV  = (const float*)d_in[7];
    const float* bV  = (const float*)d_in[8];

    const int nNodes = in_sizes[0] / IN_DIM;
    const int nEdges = in_sizes[1];

    float* out = (float*)d_out;
    const size_t nf = (size_t)nNodes * 128;

    float*  Qw       = (float*)d_ws;                 // nf f32
    uint*   KVw      = (uint*)(Qw + nf);             // nf u32
    ushort* WTw      = (ushort*)(KVw + nf);          // 384*128 bf16 (96KB)
    int*    counts   = (int*)(WTw + 384 * 128);      // nNodes
    int*    partial  = counts + nNodes;              // nNodes
    int*    srcSorted= partial + nNodes;             // nEdges
    int*    offsets  = srcSorted + nEdges;           // nNodes+1
    int*    cursor   = offsets + (nNodes + 1);       // nNodes
    int*    blockSums= cursor + nNodes;              // 64
    int*    blockOffs= blockSums + 64;               // 64

    const int nb = (nNodes + 1023) / 1024;           // 49 <= 64

    hipMemsetAsync(counts, 0, (size_t)nNodes * sizeof(int), stream);

    wtrans_kernel<<<24, 256, 0, stream>>>(WQ, WK, WV, WTw);

    int eb4 = (nEdges / 4 + 255) / 256;
    hist_kernel<<<eb4, 256, 0, stream>>>(dst, counts, nEdges);
    scan_partial<<<nb, 256, 0, stream>>>(counts, partial, blockSums, nNodes);
    scan_sums<<<1, 64, 0, stream>>>(blockSums, blockOffs, nb);
    add_offsets<<<(nNodes + 256) / 256, 256, 0, stream>>>(partial, blockOffs, offsets, cursor, nNodes, nEdges);
    scatter_kernel<<<eb4, 256, 0, stream>>>(src, dst, cursor, srcSorted, nEdges);

    proj_mfma<<<(nNodes + 63) / 64, 256, 0, stream>>>(h, (const short*)WTw, bQ, bK, bV, Qw, KVw, nNodes);

    int aggBlocks = (nNodes * 64 + 255) / 256;
    agg_kernel<<<aggBlocks, 256, 0, stream>>>(offsets, srcSorted, Qw, (const uint4*)KVw, out, nNodes);
}

// Round 7
// 156.461 us; speedup vs baseline: 5.6462x; 1.3791x over previous
//
#include <hip/hip_runtime.h>
#include <hip/hip_bf16.h>

#define IN_DIM 128
#define NUM_HEADS 8
#define OUT_DIM 16

#define BKT_SHIFT 9                       // 512 nodes per bucket
#define BKT_MASK 511
#define NB_MAX 128                        // supports nNodes <= 65536
#define SLAB_SHIFT 14                     // 16384 record slots per bucket

typedef unsigned int uint;
typedef unsigned short ushort;
using short8 = __attribute__((ext_vector_type(8))) short;
using f32x4  = __attribute__((ext_vector_type(4))) float;

__device__ inline uint bf16_rne(float x) {
    uint u = __float_as_uint(x);
    return (u + 0x7fffu + ((u >> 16) & 1u)) >> 16;
}

// ---------------- W transpose+convert: WT[n][k] bf16, n in [0,384) = {WQ|WK|WV} cols ----------------
__global__ __launch_bounds__(256) void wtrans_kernel(const float* __restrict__ WQ,
                                                     const float* __restrict__ WK,
                                                     const float* __restrict__ WV,
                                                     ushort* __restrict__ WT) {
    int tid = blockIdx.x * 256 + threadIdx.x;   // 0..6143
    if (tid >= 384 * 16) return;
    int n = tid >> 4;
    int kg = tid & 15;
    const float* W = (n < 128) ? WQ : (n < 256) ? WK : WV;
    int c = n & 127;
    short8 o;
    #pragma unroll
    for (int j = 0; j < 8; ++j) {
        float v = W[(kg * 8 + j) * 128 + c];
        o[j] = (short)bf16_rne(v);
    }
    *(short8*)(WT + (size_t)n * 128 + kg * 8) = o;
}

// ---------------- MFMA projection: 64 nodes/block, 4 waves, Q f32 + packed bf16 KV ----------------
__global__ __launch_bounds__(256) void proj_mfma(const float* __restrict__ h,
                                                 const short* __restrict__ WT,   // [384][128] bf16
                                                 const float* __restrict__ bQ,
                                                 const float* __restrict__ bK,
                                                 const float* __restrict__ bV,
                                                 float* __restrict__ Qout,
                                                 uint* __restrict__ KVout,
                                                 int nNodes) {
    __shared__ short8 hT[1024];   // 64 rows x 128 cols bf16, swizzled in 16B slots
    const int t = threadIdx.x;
    const int node0 = blockIdx.x * 64;

    #pragma unroll
    for (int i = 0; i < 4; ++i) {
        int g = t + i * 256;
        int row = g >> 4;
        int grp = g & 15;
        short8 val;
        if (node0 + row < nNodes) {
            const float* src = h + (size_t)(node0 + row) * 128 + grp * 8;
            float4 f0 = *(const float4*)src;
            float4 f1 = *(const float4*)(src + 4);
            val[0] = (short)bf16_rne(f0.x); val[1] = (short)bf16_rne(f0.y);
            val[2] = (short)bf16_rne(f0.z); val[3] = (short)bf16_rne(f0.w);
            val[4] = (short)bf16_rne(f1.x); val[5] = (short)bf16_rne(f1.y);
            val[6] = (short)bf16_rne(f1.z); val[7] = (short)bf16_rne(f1.w);
        } else {
            val = (short8)0;
        }
        hT[(row * 16 + grp) ^ (row & 7)] = val;
    }
    __syncthreads();

    const int lane = t & 63;
    const int w = t >> 6;
    const int lr = lane & 15;
    const int q = lane >> 4;

    short8 a[4];
    #pragma unroll
    for (int ks = 0; ks < 4; ++ks) {
        int row = w * 16 + lr;
        a[ks] = hT[(row * 16 + ks * 4 + q) ^ (row & 7)];
    }

    const short8* WT8 = (const short8*)WT;   // [384][16]

    #pragma unroll 2
    for (int c = 0; c < 8; ++c) {
        f32x4 accQ = {0.f, 0.f, 0.f, 0.f};
        f32x4 accK = {0.f, 0.f, 0.f, 0.f};
        f32x4 accV = {0.f, 0.f, 0.f, 0.f};
        const int nq = c * 16 + lr;
        #pragma unroll
        for (int ks = 0; ks < 4; ++ks) {
            short8 bq = WT8[(size_t)nq * 16 + ks * 4 + q];
            short8 bk = WT8[(size_t)(nq + 128) * 16 + ks * 4 + q];
            short8 bv = WT8[(size_t)(nq + 256) * 16 + ks * 4 + q];
            accQ = __builtin_amdgcn_mfma_f32_16x16x32_bf16(a[ks], bq, accQ, 0, 0, 0);
            accK = __builtin_amdgcn_mfma_f32_16x16x32_bf16(a[ks], bk, accK, 0, 0, 0);
            accV = __builtin_amdgcn_mfma_f32_16x16x32_bf16(a[ks], bv, accV, 0, 0, 0);
        }
        float biasq = bQ[nq];
        float biask = bK[nq];
        float biasv = bV[nq];
        #pragma unroll
        for (int r = 0; r < 4; ++r) {
            int node = node0 + w * 16 + q * 4 + r;
            if (node < nNodes) {
                Qout[(size_t)node * 128 + nq] = accQ[r] + biasq;
                KVout[(size_t)node * 128 + nq] =
                    bf16_rne(accK[r] + biask) | (bf16_rne(accV[r] + biasv) << 16);
            }
        }
    }
}

// ---------------- Bucketed CSR build (all per-edge atomics in LDS) ----------------
__global__ __launch_bounds__(256) void bucket_stage(const int* __restrict__ src,
                                                    const int* __restrict__ dst,
                                                    int* __restrict__ bucketCursor,
                                                    uint* __restrict__ slab,
                                                    int nEdges, int nb) {
    __shared__ int cnt[NB_MAX];
    __shared__ int base[NB_MAX];
    const int t = threadIdx.x;
    const int e0 = blockIdx.x * 4096;

    if (t < NB_MAX) cnt[t] = 0;
    __syncthreads();

    int myDst[16], mySrc[16];
    #pragma unroll
    for (int i = 0; i < 4; ++i) {
        int e = e0 + (i * 256 + t) * 4;
        if (e + 3 < nEdges) {
            int4 d4 = *(const int4*)(dst + e);
            int4 s4 = *(const int4*)(src + e);
            myDst[4*i+0] = d4.x; myDst[4*i+1] = d4.y; myDst[4*i+2] = d4.z; myDst[4*i+3] = d4.w;
            mySrc[4*i+0] = s4.x; mySrc[4*i+1] = s4.y; mySrc[4*i+2] = s4.z; mySrc[4*i+3] = s4.w;
        } else {
            #pragma unroll
            for (int k = 0; k < 4; ++k) {
                int ee = e + k;
                myDst[4*i+k] = (ee < nEdges) ? dst[ee] : -1;
                mySrc[4*i+k] = (ee < nEdges) ? src[ee] : 0;
            }
        }
    }
    #pragma unroll
    for (int i = 0; i < 16; ++i)
        if (myDst[i] >= 0) atomicAdd(&cnt[myDst[i] >> BKT_SHIFT], 1);
    __syncthreads();

    if (t < NB_MAX) {
        int c = cnt[t];
        base[t] = (t < nb && c > 0) ? atomicAdd(&bucketCursor[t], c) : 0;
    }
    __syncthreads();
    if (t < NB_MAX) cnt[t] = 0;
    __syncthreads();

    #pragma unroll
    for (int i = 0; i < 16; ++i) {
        int d = myDst[i];
        if (d >= 0) {
            int b = d >> BKT_SHIFT;
            int pos = base[b] + atomicAdd(&cnt[b], 1);
            if (pos < (1 << SLAB_SHIFT))
                slab[((size_t)b << SLAB_SHIFT) + pos] = (uint)mySrc[i] | ((uint)(d & BKT_MASK) << 17);
        }
    }
}

// 1-wave exclusive scan of up to 128 bucket counts
__global__ __launch_bounds__(64) void bucket_scan(const int* __restrict__ bc,
                                                  int* __restrict__ bo, int nb) {
    int lane = threadIdx.x;
    int v0 = (lane < nb) ? bc[lane] : 0;
    int v1 = (lane + 64 < nb) ? bc[lane + 64] : 0;
    int x0 = v0;
    #pragma unroll
    for (int off = 1; off < 64; off <<= 1) { int y = __shfl_up(x0, off); if (lane >= off) x0 += y; }
    int tot0 = __shfl(x0, 63);
    int x1 = v1;
    #pragma unroll
    for (int off = 1; off < 64; off <<= 1) { int y = __shfl_up(x1, off); if (lane >= off) x1 += y; }
    if (lane < nb) bo[lane] = x0 - v0;
    if (lane + 64 < nb) bo[lane + 64] = tot0 + x1 - v1;
}

// Sort: one block per bucket. LDS histogram + LDS scan + LDS-cursor scatter.
__global__ __launch_bounds__(256) void bucket_sort(const uint* __restrict__ slab,
                                                   const int* __restrict__ bucketCursor,
                                                   const int* __restrict__ bucketOff,
                                                   int* __restrict__ offsets,
                                                   int* __restrict__ srcSorted,
                                                   int nNodes, int nEdges) {
    __shared__ int cnt[512];
    __shared__ int wsum[4];
    const int b = blockIdx.x;
    const int t = threadIdx.x;
    const int lane = t & 63;
    const int wv = t >> 6;
    const int count = bucketCursor[b];
    const int outBase = bucketOff[b];
    const uint* rec = slab + ((size_t)b << SLAB_SHIFT);

    cnt[t] = 0; cnt[t + 256] = 0;
    __syncthreads();
    for (int i = t; i < count; i += 256)
        atomicAdd(&cnt[rec[i] >> 17], 1);
    __syncthreads();

    int c0 = cnt[2 * t], c1 = cnt[2 * t + 1];
    int s = c0 + c1;
    int x = s;
    #pragma unroll
    for (int off = 1; off < 64; off <<= 1) { int y = __shfl_up(x, off); if (lane >= off) x += y; }
    if (lane == 63) wsum[wv] = x;
    __syncthreads();
    if (t == 0) {
        int a = 0;
        #pragma unroll
        for (int w = 0; w < 4; ++w) { int tmp = wsum[w]; wsum[w] = a; a += tmp; }
    }
    __syncthreads();
    int prefix = wsum[wv] + (x - s);

    int node0 = b << BKT_SHIFT;
    int g0 = node0 + 2 * t, g1 = node0 + 2 * t + 1;
    if (g0 < nNodes) offsets[g0] = outBase + prefix;
    if (g1 < nNodes) offsets[g1] = outBase + prefix + c0;
    __syncthreads();
    cnt[2 * t] = prefix;
    cnt[2 * t + 1] = prefix + c0;
    __syncthreads();

    for (int i = t; i < count; i += 256) {
        uint r = rec[i];
        int pos = atomicAdd(&cnt[r >> 17], 1);
        srcSorted[outBase + pos] = (int)(r & 0x1ffff);
    }
    if (b == 0 && t == 0) offsets[nNodes] = nEdges;
}

// ---------------- Aggregation: one wave per dst node, 2 edges in parallel per wave ----------------
__global__ __launch_bounds__(256) void agg_kernel(const int* __restrict__ offsets,
                                                  const int* __restrict__ srcSorted,
                                                  const float* __restrict__ Q,
                                                  const uint4* __restrict__ KV,   // row = 32 uint4
                                                  float* __restrict__ out,
                                                  int nNodes) {
    int wid = (int)((blockIdx.x * (size_t)blockDim.x + threadIdx.x) >> 6);
    if (wid >= nNodes) return;
    const int lane = threadIdx.x & 63;
    const int li = lane & 31;
    const int hf = lane >> 5;
    const int beg = offsets[wid];
    const int end = offsets[wid + 1];

    // nontemporal: Q is streamed once; keep L2 for KV
    f32x4 qv = __builtin_nontemporal_load((const f32x4*)(Q + (size_t)wid * 128) + li);
    f32x4 acc = {0.f, 0.f, 0.f, 0.f};
    float zacc = 0.f;

    auto compute = [&](uint4 u, float mask) {
        float k0 = __uint_as_float(u.x << 16), v0 = __uint_as_float(u.x & 0xffff0000u);
        float k1 = __uint_as_float(u.y << 16), v1 = __uint_as_float(u.y & 0xffff0000u);
        float k2 = __uint_as_float(u.z << 16), v2 = __uint_as_float(u.z & 0xffff0000u);
        float k3 = __uint_as_float(u.w << 16), v3 = __uint_as_float(u.w & 0xffff0000u);
        float p = k0 * qv.x + k1 * qv.y + k2 * qv.z + k3 * qv.w;
        p += __shfl_xor(p, 1);
        p += __shfl_xor(p, 2);
        float e = __expf(fminf(fmaxf(p * 0.25f, -5.0f), 5.0f)) * mask;
        acc.x += v0 * e; acc.y += v1 * e; acc.z += v2 * e; acc.w += v3 * e;
        zacc += e;
    };

    int j = beg;
    for (; j + 16 <= end; j += 16) {      // 16 edges: 8 uint4 in flight per lane
        int sI[8];
        #pragma unroll
        for (int i = 0; i < 8; ++i) sI[i] = srcSorted[j + 2 * i + hf];
        uint4 u[8];
        #pragma unroll
        for (int i = 0; i < 8; ++i) u[i] = KV[(size_t)sI[i] * 32 + li];
        #pragma unroll
        for (int i = 0; i < 8; ++i) compute(u[i], 1.f);
    }
    for (; j + 8 <= end; j += 8) {        // 8 edges: 4 in flight
        int sI[4];
        #pragma unroll
        for (int i = 0; i < 4; ++i) sI[i] = srcSorted[j + 2 * i + hf];
        uint4 u[4];
        #pragma unroll
        for (int i = 0; i < 4; ++i) u[i] = KV[(size_t)sI[i] * 32 + li];
        #pragma unroll
        for (int i = 0; i < 4; ++i) compute(u[i], 1.f);
    }
    for (; j + 2 <= end; j += 2) {
        uint4 u = KV[(size_t)srcSorted[j + hf] * 32 + li];
        compute(u, 1.f);
    }
    if (j < end) {                         // odd edge: half B masked
        uint4 u = KV[(size_t)srcSorted[j] * 32 + li];
        compute(u, hf ? 0.f : 1.f);
    }

    acc.x += __shfl_xor(acc.x, 32);
    acc.y += __shfl_xor(acc.y, 32);
    acc.z += __shfl_xor(acc.z, 32);
    acc.w += __shfl_xor(acc.w, 32);
    zacc  += __shfl_xor(zacc, 32);

    if (hf == 0) {
        float inv = 1.0f / (zacc + 1e-6f);
        f32x4 o = {acc.x * inv, acc.y * inv, acc.z * inv, acc.w * inv};
        __builtin_nontemporal_store(o, (f32x4*)(out + (size_t)wid * 128) + li);
    }
}

extern "C" void kernel_launch(void* const* d_in, const int* in_sizes, int n_in,
                              void* d_out, int out_size, void* d_ws, size_t ws_size,
                              hipStream_t stream) {
    const float* h   = (const float*)d_in[0];
    const int*   src = (const int*)d_in[1];
    const int*   dst = (const int*)d_in[2];
    const float* WQ  = (const float*)d_in[3];
    const float* bQ  = (const float*)d_in[4];
    const float* WK  = (const float*)d_in[5];
    const float* bK  = (const float*)d_in[6];
    const float* WV  = (const float*)d_in[7];
    const float* bV  = (const float*)d_in[8];

    const int nNodes = in_sizes[0] / IN_DIM;
    const int nEdges = in_sizes[1];
    const int nb = (nNodes + (1 << BKT_SHIFT) - 1) >> BKT_SHIFT;   // 98 for 50000

    float* out = (float*)d_out;
    const size_t nf = (size_t)nNodes * 128;

    float*  Qw          = (float*)d_ws;                  // nf f32
    uint*   KVw         = (uint*)(Qw + nf);              // nf u32
    ushort* WTw         = (ushort*)(KVw + nf);           // 384*128 bf16
    int*    bucketCursor= (int*)(WTw + 384 * 128);       // NB_MAX
    int*    bucketOff   = bucketCursor + NB_MAX;         // NB_MAX
    int*    offsets     = bucketOff + NB_MAX;            // nNodes+1
    int*    srcSorted   = offsets + (nNodes + 1);        // nEdges
    uint*   slab        = (uint*)(srcSorted + nEdges);   // NB_MAX << SLAB_SHIFT (8MB)

    (void)hipMemsetAsync(bucketCursor, 0, NB_MAX * sizeof(int), stream);

    wtrans_kernel<<<24, 256, 0, stream>>>(WQ, WK, WV, WTw);

    // CSR build
    int sb = (nEdges + 4095) / 4096;
    bucket_stage<<<sb, 256, 0, stream>>>(src, dst, bucketCursor, slab, nEdges, nb);
    bucket_scan<<<1, 64, 0, stream>>>(bucketCursor, bucketOff, nb);
    bucket_sort<<<nb, 256, 0, stream>>>(slab, bucketCursor, bucketOff, offsets, srcSorted, nNodes, nEdges);

    // projections
    proj_mfma<<<(nNodes + 63) / 64, 256, 0, stream>>>(h, (const short*)WTw, bQ, bK, bV, Qw, KVw, nNodes);

    // aggregation
    int aggBlocks = (nNodes * 64 + 255) / 256;
    agg_kernel<<<aggBlocks, 256, 0, stream>>>(offsets, srcSorted, Qw, (const uint4*)KVw, out, nNodes);
}

// Round 8
// 148.705 us; speedup vs baseline: 5.9406x; 1.0522x over previous
//
#include <hip/hip_runtime.h>
#include <hip/hip_bf16.h>

#define IN_DIM 128
#define NUM_HEADS 8
#define OUT_DIM 16

#define BKT_SHIFT 9                       // 512 nodes per bucket
#define BKT_MASK 511
#define NB_MAX 128                        // supports nNodes <= 65536
#define SLAB_SHIFT 14                     // 16384 record slots per bucket

typedef unsigned int uint;
typedef unsigned short ushort;
using short8 = __attribute__((ext_vector_type(8))) short;
using f32x4  = __attribute__((ext_vector_type(4))) float;
using u32x2  = __attribute__((ext_vector_type(2))) uint;

__device__ inline uint bf16_rne(float x) {
    uint u = __float_as_uint(x);
    return (u + 0x7fffu + ((u >> 16) & 1u)) >> 16;
}

// ---------------- Fused: bucket_stage (blocks < sb) + W transpose (blocks >= sb) ----------------
// Stage: per-wave privatized LDS counters; records src | (dstLocal << 17).
__global__ __launch_bounds__(256) void stage_wtrans(const int* __restrict__ src,
                                                    const int* __restrict__ dst,
                                                    int* __restrict__ bucketCursor,
                                                    uint* __restrict__ slab,
                                                    const float* __restrict__ WQ,
                                                    const float* __restrict__ WK,
                                                    const float* __restrict__ WV,
                                                    ushort* __restrict__ WT,
                                                    int nEdges, int nb, int sb) {
    const int t = threadIdx.x;

    if ((int)blockIdx.x >= sb) {
        // ---- W transpose+convert: WT[n][k] bf16, n in [0,384) ----
        int tid = (blockIdx.x - sb) * 256 + t;      // 0..6143
        if (tid >= 384 * 16) return;
        int n = tid >> 4;
        int kg = tid & 15;
        const float* W = (n < 128) ? WQ : (n < 256) ? WK : WV;
        int c = n & 127;
        short8 o;
        #pragma unroll
        for (int j = 0; j < 8; ++j) {
            float v = W[(kg * 8 + j) * 128 + c];
            o[j] = (short)bf16_rne(v);
        }
        *(short8*)(WT + (size_t)n * 128 + kg * 8) = o;
        return;
    }

    __shared__ int cnt[4][NB_MAX];     // per-wave counts, then per-wave cursors
    __shared__ int base[4][NB_MAX];    // per-wave write bases
    const int wv = t >> 6;
    const int e0 = blockIdx.x * 4096;

    for (int i = t; i < 4 * NB_MAX; i += 256) ((int*)cnt)[i] = 0;
    __syncthreads();

    int myDst[16], mySrc[16];
    #pragma unroll
    for (int i = 0; i < 4; ++i) {
        int e = e0 + (i * 256 + t) * 4;
        if (e + 3 < nEdges) {
            int4 d4 = *(const int4*)(dst + e);
            int4 s4 = *(const int4*)(src + e);
            myDst[4*i+0] = d4.x; myDst[4*i+1] = d4.y; myDst[4*i+2] = d4.z; myDst[4*i+3] = d4.w;
            mySrc[4*i+0] = s4.x; mySrc[4*i+1] = s4.y; mySrc[4*i+2] = s4.z; mySrc[4*i+3] = s4.w;
        } else {
            #pragma unroll
            for (int k = 0; k < 4; ++k) {
                int ee = e + k;
                myDst[4*i+k] = (ee < nEdges) ? dst[ee] : -1;
                mySrc[4*i+k] = (ee < nEdges) ? src[ee] : 0;
            }
        }
    }
    #pragma unroll
    for (int i = 0; i < 16; ++i)
        if (myDst[i] >= 0) atomicAdd(&cnt[wv][myDst[i] >> BKT_SHIFT], 1);
    __syncthreads();

    if (t < NB_MAX) {
        int c0 = cnt[0][t], c1 = cnt[1][t], c2 = cnt[2][t], c3 = cnt[3][t];
        int tot = c0 + c1 + c2 + c3;
        int gbase = (t < nb && tot > 0) ? atomicAdd(&bucketCursor[t], tot) : 0;
        base[0][t] = gbase;
        base[1][t] = gbase + c0;
        base[2][t] = gbase + c0 + c1;
        base[3][t] = gbase + c0 + c1 + c2;
    }
    __syncthreads();
    for (int i = t; i < 4 * NB_MAX; i += 256) ((int*)cnt)[i] = 0;
    __syncthreads();

    #pragma unroll
    for (int i = 0; i < 16; ++i) {
        int d = myDst[i];
        if (d >= 0) {
            int b = d >> BKT_SHIFT;
            int pos = base[wv][b] + atomicAdd(&cnt[wv][b], 1);
            if (pos < (1 << SLAB_SHIFT))
                slab[((size_t)b << SLAB_SHIFT) + pos] = (uint)mySrc[i] | ((uint)(d & BKT_MASK) << 17);
        }
    }
}

// ---------------- Sort: one block per bucket; computes its own outBase from counts ----------------
__global__ __launch_bounds__(256) void bucket_sort(const uint* __restrict__ slab,
                                                   const int* __restrict__ bucketCursor,
                                                   int* __restrict__ offsets,
                                                   int* __restrict__ srcSorted,
                                                   int nNodes, int nEdges, int nb) {
    __shared__ int cnt[512];
    __shared__ int wsum[4];
    __shared__ int sOutBase;
    const int b = blockIdx.x;
    const int t = threadIdx.x;
    const int lane = t & 63;
    const int wv = t >> 6;
    const int count = bucketCursor[b];
    const uint* rec = slab + ((size_t)b << SLAB_SHIFT);

    // outBase = sum of counts of buckets before b (wave 0)
    if (t < 64) {
        int acc = 0;
        for (int i = t; i < b; i += 64) acc += bucketCursor[i];
        #pragma unroll
        for (int off = 32; off; off >>= 1) acc += __shfl_down(acc, off);
        if (t == 0) sOutBase = acc;
    }

    cnt[t] = 0; cnt[t + 256] = 0;
    __syncthreads();
    for (int i = t; i < count; i += 256)
        atomicAdd(&cnt[rec[i] >> 17], 1);
    __syncthreads();

    int c0 = cnt[2 * t], c1 = cnt[2 * t + 1];
    int s = c0 + c1;
    int x = s;
    #pragma unroll
    for (int off = 1; off < 64; off <<= 1) { int y = __shfl_up(x, off); if (lane >= off) x += y; }
    if (lane == 63) wsum[wv] = x;
    __syncthreads();
    if (t == 0) {
        int a = 0;
        #pragma unroll
        for (int w = 0; w < 4; ++w) { int tmp = wsum[w]; wsum[w] = a; a += tmp; }
    }
    __syncthreads();
    int prefix = wsum[wv] + (x - s);
    const int outBase = sOutBase;

    int node0 = b << BKT_SHIFT;
    int g0 = node0 + 2 * t, g1 = node0 + 2 * t + 1;
    if (g0 < nNodes) offsets[g0] = outBase + prefix;
    if (g1 < nNodes) offsets[g1] = outBase + prefix + c0;
    __syncthreads();
    cnt[2 * t] = prefix;
    cnt[2 * t + 1] = prefix + c0;
    __syncthreads();

    for (int i = t; i < count; i += 256) {
        uint r = rec[i];
        int pos = atomicAdd(&cnt[r >> 17], 1);
        srcSorted[outBase + pos] = (int)(r & 0x1ffff);
    }
    if (b == 0 && t == 0) offsets[nNodes] = nEdges;
}

// ---------------- MFMA projection: Q packed bf16 pairs, KV packed bf16 pairs ----------------
__global__ __launch_bounds__(256) void proj_mfma(const float* __restrict__ h,
                                                 const short* __restrict__ WT,   // [384][128] bf16
                                                 const float* __restrict__ bQ,
                                                 const float* __restrict__ bK,
                                                 const float* __restrict__ bV,
                                                 uint* __restrict__ Qout,        // [N][64] bf16 pairs
                                                 uint* __restrict__ KVout,       // [N][128] K|V pairs
                                                 int nNodes) {
    __shared__ short8 hT[1024];   // 64 rows x 128 cols bf16, swizzled in 16B slots
    const int t = threadIdx.x;
    const int node0 = blockIdx.x * 64;

    #pragma unroll
    for (int i = 0; i < 4; ++i) {
        int g = t + i * 256;
        int row = g >> 4;
        int grp = g & 15;
        short8 val;
        if (node0 + row < nNodes) {
            const float* srcp = h + (size_t)(node0 + row) * 128 + grp * 8;
            float4 f0 = *(const float4*)srcp;
            float4 f1 = *(const float4*)(srcp + 4);
            val[0] = (short)bf16_rne(f0.x); val[1] = (short)bf16_rne(f0.y);
            val[2] = (short)bf16_rne(f0.z); val[3] = (short)bf16_rne(f0.w);
            val[4] = (short)bf16_rne(f1.x); val[5] = (short)bf16_rne(f1.y);
            val[6] = (short)bf16_rne(f1.z); val[7] = (short)bf16_rne(f1.w);
        } else {
            val = (short8)0;
        }
        hT[(row * 16 + grp) ^ (row & 7)] = val;
    }
    __syncthreads();

    const int lane = t & 63;
    const int w = t >> 6;
    const int lr = lane & 15;
    const int q = lane >> 4;

    short8 a[4];
    #pragma unroll
    for (int ks = 0; ks < 4; ++ks) {
        int row = w * 16 + lr;
        a[ks] = hT[(row * 16 + ks * 4 + q) ^ (row & 7)];
    }

    const short8* WT8 = (const short8*)WT;   // [384][16]

    #pragma unroll 2
    for (int c = 0; c < 8; ++c) {
        f32x4 accQ = {0.f, 0.f, 0.f, 0.f};
        f32x4 accK = {0.f, 0.f, 0.f, 0.f};
        f32x4 accV = {0.f, 0.f, 0.f, 0.f};
        const int nq = c * 16 + lr;
        #pragma unroll
        for (int ks = 0; ks < 4; ++ks) {
            short8 bq = WT8[(size_t)nq * 16 + ks * 4 + q];
            short8 bk = WT8[(size_t)(nq + 128) * 16 + ks * 4 + q];
            short8 bv = WT8[(size_t)(nq + 256) * 16 + ks * 4 + q];
            accQ = __builtin_amdgcn_mfma_f32_16x16x32_bf16(a[ks], bq, accQ, 0, 0, 0);
            accK = __builtin_amdgcn_mfma_f32_16x16x32_bf16(a[ks], bk, accK, 0, 0, 0);
            accV = __builtin_amdgcn_mfma_f32_16x16x32_bf16(a[ks], bv, accV, 0, 0, 0);
        }
        float biasq = bQ[nq];
        float biask = bK[nq];
        float biasv = bV[nq];
        #pragma unroll
        for (int r = 0; r < 4; ++r) {
            int node = node0 + w * 16 + q * 4 + r;
            float qval = accQ[r] + biasq;
            float qpart = __shfl_xor(qval, 1);    // partner col (lr^1), same node
            if (node < nNodes) {
                if ((lr & 1) == 0)
                    Qout[(size_t)node * 64 + (nq >> 1)] = bf16_rne(qval) | (bf16_rne(qpart) << 16);
                KVout[(size_t)node * 128 + nq] =
                    bf16_rne(accK[r] + biask) | (bf16_rne(accV[r] + biasv) << 16);
            }
        }
    }
}

// ---------------- Aggregation: one wave per dst node, 2 edges in parallel per wave ----------------
// lanes 0-31 = edge stream A, lanes 32-63 = edge stream B. Lane li owns dims 4li..4li+3.
__global__ __launch_bounds__(256) void agg_kernel(const int* __restrict__ offsets,
                                                  const int* __restrict__ srcSorted,
                                                  const uint* __restrict__ Q,     // [N][64] bf16 pairs
                                                  const uint4* __restrict__ KV,   // row = 32 uint4
                                                  float* __restrict__ out,
                                                  int nNodes) {
    int wid = (int)((blockIdx.x * (size_t)blockDim.x + threadIdx.x) >> 6);
    if (wid >= nNodes) return;
    const int lane = threadIdx.x & 63;
    const int li = lane & 31;
    const int hf = lane >> 5;
    const int beg = offsets[wid];
    const int end = offsets[wid + 1];

    // Q is streamed once; nontemporal keeps L2 for KV
    u32x2 qp = __builtin_nontemporal_load((const u32x2*)(Q + (size_t)wid * 64) + li);
    f32x4 qv;
    qv.x = __uint_as_float(qp.x << 16);
    qv.y = __uint_as_float(qp.x & 0xffff0000u);
    qv.z = __uint_as_float(qp.y << 16);
    qv.w = __uint_as_float(qp.y & 0xffff0000u);

    f32x4 acc = {0.f, 0.f, 0.f, 0.f};
    float zacc = 0.f;

    auto compute = [&](uint4 u, float mask) {
        float k0 = __uint_as_float(u.x << 16), v0 = __uint_as_float(u.x & 0xffff0000u);
        float k1 = __uint_as_float(u.y << 16), v1 = __uint_as_float(u.y & 0xffff0000u);
        float k2 = __uint_as_float(u.z << 16), v2 = __uint_as_float(u.z & 0xffff0000u);
        float k3 = __uint_as_float(u.w << 16), v3 = __uint_as_float(u.w & 0xffff0000u);
        float p = k0 * qv.x + k1 * qv.y + k2 * qv.z + k3 * qv.w;
        p += __shfl_xor(p, 1);
        p += __shfl_xor(p, 2);
        float e = __expf(fminf(fmaxf(p * 0.25f, -5.0f), 5.0f)) * mask;
        acc.x += v0 * e; acc.y += v1 * e; acc.z += v2 * e; acc.w += v3 * e;
        zacc += e;
    };

    int j = beg;
    for (; j + 8 <= end; j += 8) {        // 8 edges: 4 uint4 in flight per lane
        int sI[4];
        #pragma unroll
        for (int i = 0; i < 4; ++i) sI[i] = srcSorted[j + 2 * i + hf];
        uint4 u[4];
        #pragma unroll
        for (int i = 0; i < 4; ++i) u[i] = KV[(size_t)sI[i] * 32 + li];
        #pragma unroll
        for (int i = 0; i < 4; ++i) compute(u[i], 1.f);
    }
    for (; j + 2 <= end; j += 2) {
        uint4 u = KV[(size_t)srcSorted[j + hf] * 32 + li];
        compute(u, 1.f);
    }
    if (j < end) {                         // odd edge: half B masked
        uint4 u = KV[(size_t)srcSorted[j] * 32 + li];
        compute(u, hf ? 0.f : 1.f);
    }

    acc.x += __shfl_xor(acc.x, 32);
    acc.y += __shfl_xor(acc.y, 32);
    acc.z += __shfl_xor(acc.z, 32);
    acc.w += __shfl_xor(acc.w, 32);
    zacc  += __shfl_xor(zacc, 32);

    if (hf == 0) {
        float inv = 1.0f / (zacc + 1e-6f);
        f32x4 o = {acc.x * inv, acc.y * inv, acc.z * inv, acc.w * inv};
        __builtin_nontemporal_store(o, (f32x4*)(out + (size_t)wid * 128) + li);
    }
}

extern "C" void kernel_launch(void* const* d_in, const int* in_sizes, int n_in,
                              void* d_out, int out_size, void* d_ws, size_t ws_size,
                              hipStream_t stream) {
    const float* h   = (const float*)d_in[0];
    const int*   src = (const int*)d_in[1];
    const int*   dst = (const int*)d_in[2];
    const float* WQ  = (const float*)d_in[3];
    const float* bQ  = (const float*)d_in[4];
    const float* WK  = (const float*)d_in[5];
    const float* bK  = (const float*)d_in[6];
    const float* WV  = (const float*)d_in[7];
    const float* bV  = (const float*)d_in[8];

    const int nNodes = in_sizes[0] / IN_DIM;
    const int nEdges = in_sizes[1];
    const int nb = (nNodes + (1 << BKT_SHIFT) - 1) >> BKT_SHIFT;   // 98 for 50000

    float* out = (float*)d_out;
    const size_t nf = (size_t)nNodes * 128;

    uint*   Qw          = (uint*)d_ws;                   // nNodes*64 u32 (bf16 pairs)
    uint*   KVw         = Qw + (size_t)nNodes * 64;      // nf u32
    ushort* WTw         = (ushort*)(KVw + nf);           // 384*128 bf16
    int*    bucketCursor= (int*)(WTw + 384 * 128);       // NB_MAX
    int*    offsets     = bucketCursor + NB_MAX;         // nNodes+1
    int*    srcSorted   = offsets + (nNodes + 1);        // nEdges
    uint*   slab        = (uint*)(srcSorted + nEdges);   // NB_MAX << SLAB_SHIFT (8MB)

    (void)hipMemsetAsync(bucketCursor, 0, NB_MAX * sizeof(int), stream);

    // fused: CSR stage (blocks < sb) + W transpose (24 extra blocks)
    int sb = (nEdges + 4095) / 4096;
    stage_wtrans<<<sb + 24, 256, 0, stream>>>(src, dst, bucketCursor, slab,
                                              WQ, WK, WV, WTw, nEdges, nb, sb);
    bucket_sort<<<nb, 256, 0, stream>>>(slab, bucketCursor, offsets, srcSorted, nNodes, nEdges, nb);

    proj_mfma<<<(nNodes + 63) / 64, 256, 0, stream>>>(h, (const short*)WTw, bQ, bK, bV, Qw, KVw, nNodes);

    int aggBlocks = (nNodes * 64 + 255) / 256;
    agg_kernel<<<aggBlocks, 256, 0, stream>>>(offsets, srcSorted, Qw, (const uint4*)KVw, out, nNodes);
}